// Round 5
// baseline (423.144 us; speedup 1.0000x reference)
//
#include <hip/hip_runtime.h>
#include <math.h>

#define NN 50000
#define EE 1600000
#define HEADS 4
#define OUTC 64
#define NEG_SLOPE 0.2f

#define BM 64
#define BK 64

#define NB 196            // ceil(NN/256) coarse bins (dst>>8)
#define RECTOT (EE + NN)  // edges + self-loops
#define PCHUNK 4096       // records per partition block
#define SEGCAP 12288      // LDS staging capacity for one segment
#define PHB 12500         // blocks per head-phase in aggr (4 nodes/block)

// ---------------- CSR build: MSD counting sort by dst ----------------

__global__ void initcsr_kernel(int* __restrict__ hist1, int* __restrict__ fill1,
                               int* __restrict__ rowptr) {
    int t = threadIdx.x;
    if (t < NB) { hist1[t] = 0; fill1[t] = 0; }
    if (t == 0) rowptr[NN] = RECTOT;
}

__global__ __launch_bounds__(256) void hist_hi_kernel(const int* __restrict__ dst,
                                                      int* __restrict__ hist1) {
    __shared__ int lh[NB];
    int t = threadIdx.x;
    if (t < NB) lh[t] = 0;
    __syncthreads();
    int base = blockIdx.x * PCHUNK;
    #pragma unroll
    for (int j = 0; j < 16; ++j) {
        int i = base + j * 256 + t;
        if (i < RECTOT) {
            int d = (i < EE) ? dst[i] : (i - EE);
            atomicAdd(&lh[d >> 8], 1);
        }
    }
    __syncthreads();
    if (t < NB && lh[t]) atomicAdd(&hist1[t], lh[t]);
}

__global__ void scan_hi_kernel(const int* __restrict__ hist1, int* __restrict__ binStart) {
    int t = threadIdx.x, lane = t & 63, w = t >> 6;
    __shared__ int wsum[4];
    int v = (t < NB) ? hist1[t] : 0;
    int s = v;
    #pragma unroll
    for (int off = 1; off < 64; off <<= 1) {
        int u = __shfl_up(s, off);
        if (lane >= off) s += u;
    }
    if (lane == 63) wsum[w] = s;
    __syncthreads();
    int add = 0;
    for (int i = 0; i < w; ++i) add += wsum[i];
    int excl = add + s - v;
    if (t <= NB) binStart[t] = excl;
}

__global__ __launch_bounds__(256) void partition_kernel(
        const int* __restrict__ src, const int* __restrict__ dst,
        const int* __restrict__ binStart, int* __restrict__ fill1,
        uint2* __restrict__ bucket) {
    __shared__ int bh[NB], bbase[NB], sbase[NB];
    int t = threadIdx.x;
    if (t < NB) { bh[t] = 0; sbase[t] = binStart[t]; }
    __syncthreads();
    int base = blockIdx.x * PCHUNK;
    int dv[16], sv[16], lr[16];
    #pragma unroll
    for (int j = 0; j < 16; ++j) {
        int i = base + j * 256 + t;
        bool valid = i < RECTOT;
        int d = -1, s = 0;
        if (valid) {
            if (i < EE) { d = dst[i]; s = src[i]; }
            else        { d = i - EE; s = d; }
        }
        dv[j] = d; sv[j] = s;
        lr[j] = valid ? atomicAdd(&bh[d >> 8], 1) : 0;
    }
    __syncthreads();
    if (t < NB && bh[t]) bbase[t] = atomicAdd(&fill1[t], bh[t]);
    __syncthreads();
    #pragma unroll
    for (int j = 0; j < 16; ++j) {
        if (dv[j] >= 0) {
            int bin = dv[j] >> 8;
            bucket[sbase[bin] + bbase[bin] + lr[j]] =
                make_uint2((unsigned)dv[j], (unsigned)sv[j]);
        }
    }
}

// one block per coarse bin: LDS counting sort by dst&255, emit ushort col + rowptr
__global__ __launch_bounds__(256) void seg_sort_kernel(
        const uint2* __restrict__ bucket, const int* __restrict__ binStart,
        int* __restrict__ rowptr, unsigned short* __restrict__ col) {
    __shared__ uint2 stage[SEGCAP];
    __shared__ int h2[256], b2[256], c2[256];
    __shared__ int wsum[4];
    int t = threadIdx.x, lane = t & 63, w = t >> 6;
    int b = blockIdx.x;
    int segbase = binStart[b], segend = binStart[b + 1];
    int len = segend - segbase;
    h2[t] = 0; c2[t] = 0;
    __syncthreads();
    bool inLds = (len <= SEGCAP);
    if (inLds) {
        for (int i = t; i < len; i += 256) {
            uint2 r = bucket[segbase + i];
            stage[i] = r;
            atomicAdd(&h2[r.x & 255], 1);
        }
    } else {
        for (int i = t; i < len; i += 256) {
            uint2 r = bucket[segbase + i];
            atomicAdd(&h2[r.x & 255], 1);
        }
    }
    __syncthreads();
    int v = h2[t], s = v;
    #pragma unroll
    for (int off = 1; off < 64; off <<= 1) {
        int u = __shfl_up(s, off);
        if (lane >= off) s += u;
    }
    if (lane == 63) wsum[w] = s;
    __syncthreads();
    int add = 0;
    for (int i = 0; i < w; ++i) add += wsum[i];
    int excl = add + s - v;
    b2[t] = excl;
    int d = (b << 8) + t;
    if (d < NN) rowptr[d] = segbase + excl;
    __syncthreads();
    if (inLds) {
        for (int i = t; i < len; i += 256) {
            uint2 r = stage[i];
            int low = r.x & 255;
            int pos = b2[low] + atomicAdd(&c2[low], 1);
            col[segbase + pos] = (unsigned short)r.y;
        }
    } else {
        for (int i = t; i < len; i += 256) {
            uint2 r = bucket[segbase + i];
            int low = r.x & 255;
            int pos = b2[low] + atomicAdd(&c2[low], 1);
            col[segbase + pos] = (unsigned short)r.y;
        }
    }
}

// ---------------- tiled GEMM + fused attention-logit epilogue ----------------
// h / a_s / a_d written HEAD-MAJOR: h[head][node][16], a_s[head][node].
__global__ __launch_bounds__(256) void gemm_att_kernel(
        const float* __restrict__ x, const float* __restrict__ W,
        const float* __restrict__ att_src, const float* __restrict__ att_dst,
        float* __restrict__ h, float* __restrict__ a_s, float* __restrict__ a_d,
        int n, int K) {
    __shared__ float Xs[BM][BK + 4];
    __shared__ float Ws[BK][OUTC + 4];
    int tid = (int)threadIdx.x;
    int tx = tid & 15, ty = tid >> 4;
    int row0 = blockIdx.x * BM;

    float acc[4][4] = {};

    for (int k0 = 0; k0 < K; k0 += BK) {
        {
            int r = tid >> 2;
            int kc = (tid & 3) * 16;
            int row = row0 + r; if (row >= n) row = n - 1;
            const float4* xp = (const float4*)(x + (size_t)row * K + k0 + kc);
            float4 v0 = xp[0], v1 = xp[1], v2 = xp[2], v3 = xp[3];
            *(float4*)&Xs[r][kc]      = v0;
            *(float4*)&Xs[r][kc + 4]  = v1;
            *(float4*)&Xs[r][kc + 8]  = v2;
            *(float4*)&Xs[r][kc + 12] = v3;
        }
        {
            int k = tid >> 2;
            int c = (tid & 3) * 16;
            const float4* wp = (const float4*)(W + (size_t)(k0 + k) * OUTC + c);
            float4 v0 = wp[0], v1 = wp[1], v2 = wp[2], v3 = wp[3];
            *(float4*)&Ws[k][c]      = v0;
            *(float4*)&Ws[k][c + 4]  = v1;
            *(float4*)&Ws[k][c + 8]  = v2;
            *(float4*)&Ws[k][c + 12] = v3;
        }
        __syncthreads();
        #pragma unroll 8
        for (int k = 0; k < BK; ++k) {
            float4 wv = *(const float4*)&Ws[k][tx * 4];
            float x0 = Xs[ty * 4 + 0][k];
            float x1 = Xs[ty * 4 + 1][k];
            float x2 = Xs[ty * 4 + 2][k];
            float x3 = Xs[ty * 4 + 3][k];
            acc[0][0] = fmaf(x0, wv.x, acc[0][0]); acc[0][1] = fmaf(x0, wv.y, acc[0][1]);
            acc[0][2] = fmaf(x0, wv.z, acc[0][2]); acc[0][3] = fmaf(x0, wv.w, acc[0][3]);
            acc[1][0] = fmaf(x1, wv.x, acc[1][0]); acc[1][1] = fmaf(x1, wv.y, acc[1][1]);
            acc[1][2] = fmaf(x1, wv.z, acc[1][2]); acc[1][3] = fmaf(x1, wv.w, acc[1][3]);
            acc[2][0] = fmaf(x2, wv.x, acc[2][0]); acc[2][1] = fmaf(x2, wv.y, acc[2][1]);
            acc[2][2] = fmaf(x2, wv.z, acc[2][2]); acc[2][3] = fmaf(x2, wv.w, acc[2][3]);
            acc[3][0] = fmaf(x3, wv.x, acc[3][0]); acc[3][1] = fmaf(x3, wv.y, acc[3][1]);
            acc[3][2] = fmaf(x3, wv.z, acc[3][2]); acc[3][3] = fmaf(x3, wv.w, acc[3][3]);
        }
        __syncthreads();
    }

    float as0 = att_src[tx * 4 + 0], as1 = att_src[tx * 4 + 1];
    float as2 = att_src[tx * 4 + 2], as3 = att_src[tx * 4 + 3];
    float ad0 = att_dst[tx * 4 + 0], ad1 = att_dst[tx * 4 + 1];
    float ad2 = att_dst[tx * 4 + 2], ad3 = att_dst[tx * 4 + 3];
    int head = tx >> 2;
    float* hh = h + (size_t)head * NN * 16 + (tx & 3) * 4;
    #pragma unroll
    for (int i = 0; i < 4; ++i) {
        int row = row0 + ty * 4 + i;
        bool ok = row < n;
        if (ok) {
            float4 hv = make_float4(acc[i][0], acc[i][1], acc[i][2], acc[i][3]);
            *(float4*)(hh + row * 16) = hv;
        }
        float ps = acc[i][0] * as0 + acc[i][1] * as1 + acc[i][2] * as2 + acc[i][3] * as3;
        float pd = acc[i][0] * ad0 + acc[i][1] * ad1 + acc[i][2] * ad2 + acc[i][3] * ad3;
        ps += __shfl_xor(ps, 1); ps += __shfl_xor(ps, 2);
        pd += __shfl_xor(pd, 1); pd += __shfl_xor(pd, 2);
        if (ok && (tx & 3) == 0) {
            a_s[head * NN + row] = ps;
            a_d[head * NN + row] = pd;
        }
    }
}

// ---------------- segment softmax + aggregation, head-phased ----------------
// grid = 4 head-phases x 12500 blocks; one phase's gather slice (3.2 MB)
// fits per-XCD L2. Wave = 1 node: 8 edge-slots x 8 channel-lanes (float2).
__global__ __launch_bounds__(256) void gat_aggr_kernel(
        const int* __restrict__ rowptr, const unsigned short* __restrict__ col,
        const float* __restrict__ h, const float* __restrict__ a_s,
        const float* __restrict__ a_d, const float* __restrict__ bias,
        float* __restrict__ out, int n, int do_relu) {
    int head = (int)(blockIdx.x / PHB);
    int node = (int)(blockIdx.x % PHB) * 4 + (int)(threadIdx.x >> 6);
    if (node >= n) return;
    int lane = (int)(threadIdx.x & 63);
    int slot = lane >> 3;   // edge slot 0..7
    int cl   = lane & 7;    // float2 pair: channels 2cl,2cl+1 of this head

    int beg = rowptr[node], end = rowptr[node + 1];
    float ad_h = a_d[head * NN + node];
    const float*  __restrict__ asp = a_s + head * NN;
    const float2* __restrict__ hp  = (const float2*)(h + (size_t)head * NN * 16);

    float ax = 0.f, ay = 0.f, den = 0.f;
    for (int e = beg + slot; e < end; e += 8) {
        int s = (int)col[e];
        float asv = asp[s];
        float2 hv = hp[(s << 3) | cl];
        float xv = asv + ad_h; xv = fmaxf(xv, NEG_SLOPE * xv);
        float ex = __expf(xv);
        ax = fmaf(ex, hv.x, ax);
        ay = fmaf(ex, hv.y, ay);
        den += ex;
    }
    // reduce across the slot axis (lane bits 3..5)
    ax  += __shfl_xor(ax, 8);  ay  += __shfl_xor(ay, 8);  den += __shfl_xor(den, 8);
    ax  += __shfl_xor(ax, 16); ay  += __shfl_xor(ay, 16); den += __shfl_xor(den, 16);
    ax  += __shfl_xor(ax, 32); ay  += __shfl_xor(ay, 32); den += __shfl_xor(den, 32);
    if (slot == 0) {
        float inv = 1.0f / (den + 1e-16f);
        float2 bv = ((const float2*)bias)[head * 8 + cl];
        float rx = fmaf(ax, inv, bv.x);
        float ry = fmaf(ay, inv, bv.y);
        if (do_relu) { rx = fmaxf(rx, 0.f); ry = fmaxf(ry, 0.f); }
        ((float2*)out)[node * 32 + head * 8 + cl] = make_float2(rx, ry);
    }
}

extern "C" void kernel_launch(void* const* d_in, const int* in_sizes, int n_in,
                              void* d_out, int out_size, void* d_ws, size_t ws_size,
                              hipStream_t stream) {
    const float* x  = (const float*)d_in[0];
    const int*   ei = (const int*)d_in[1];
    const int*   srcv = ei;         // edge_index[0]
    const int*   dstv = ei + EE;    // edge_index[1]

    const float* W[3]  = { (const float*)d_in[2], (const float*)d_in[6],  (const float*)d_in[10] };
    const float* AS[3] = { (const float*)d_in[3], (const float*)d_in[7],  (const float*)d_in[11] };
    const float* AD[3] = { (const float*)d_in[4], (const float*)d_in[8],  (const float*)d_in[12] };
    const float* B[3]  = { (const float*)d_in[5], (const float*)d_in[9],  (const float*)d_in[13] };

    char* ws = (char*)d_ws;
    size_t off = 0;
    auto carve = [&](size_t bytes) -> char* {
        char* p = ws + off;
        off = (off + bytes + 255) & ~(size_t)255;
        return p;
    };
    int*            rowptr   = (int*)carve((NN + 1) * sizeof(int));
    int*            hist1    = (int*)carve(NB * sizeof(int));
    int*            fill1    = (int*)carve(NB * sizeof(int));
    int*            binStart = (int*)carve((NB + 1) * sizeof(int));
    unsigned short* colv     = (unsigned short*)carve((size_t)RECTOT * sizeof(unsigned short));
    // bucket (13.2 MB) dead after seg_sort; hbuf (12.8 MB) first written after. Alias.
    char*  regionA  = carve((size_t)RECTOT * sizeof(uint2));
    uint2* bucket   = (uint2*)regionA;
    float* hbuf     = (float*)regionA;               // head-major [4][NN][16]
    float* xbuf     = (float*)carve((size_t)NN * OUTC * sizeof(float));
    float* a_s      = (float*)carve((size_t)HEADS * NN * sizeof(float));  // [4][NN]
    float* a_d      = (float*)carve((size_t)HEADS * NN * sizeof(float));  // [4][NN]

    // ---- CSR build: MSD counting sort (graph identical across layers) ----
    int pgrid = (RECTOT + PCHUNK - 1) / PCHUNK;
    initcsr_kernel<<<1, 256, 0, stream>>>(hist1, fill1, rowptr);
    hist_hi_kernel<<<pgrid, 256, 0, stream>>>(dstv, hist1);
    scan_hi_kernel<<<1, 256, 0, stream>>>(hist1, binStart);
    partition_kernel<<<pgrid, 256, 0, stream>>>(srcv, dstv, binStart, fill1, bucket);
    seg_sort_kernel<<<NB, 256, 0, stream>>>(bucket, binStart, rowptr, colv);

    int grid_gemm = (NN + BM - 1) / BM;
    int grid_aggr = HEADS * PHB;

    // ---- layer 0 (K=128) ----
    gemm_att_kernel<<<grid_gemm, 256, 0, stream>>>(x, W[0], AS[0], AD[0], hbuf, a_s, a_d, NN, 128);
    gat_aggr_kernel<<<grid_aggr, 256, 0, stream>>>(rowptr, colv, hbuf, a_s, a_d, B[0], xbuf, NN, 1);
    // ---- layer 1 (K=64) ----
    gemm_att_kernel<<<grid_gemm, 256, 0, stream>>>(xbuf, W[1], AS[1], AD[1], hbuf, a_s, a_d, NN, 64);
    gat_aggr_kernel<<<grid_aggr, 256, 0, stream>>>(rowptr, colv, hbuf, a_s, a_d, B[1], xbuf, NN, 1);
    // ---- layer 2 (K=64, no relu) -> d_out ----
    gemm_att_kernel<<<grid_gemm, 256, 0, stream>>>(xbuf, W[2], AS[2], AD[2], hbuf, a_s, a_d, NN, 64);
    gat_aggr_kernel<<<grid_aggr, 256, 0, stream>>>(rowptr, colv, hbuf, a_s, a_d, B[2], (float*)d_out, NN, 0);
}

// Round 6
// 281.038 us; speedup vs baseline: 1.5056x; 1.5056x over previous
//
#include <hip/hip_runtime.h>
#include <math.h>

#define NN 50000
#define EE 1600000
#define HEADS 4
#define OUTC 64
#define NEG_SLOPE 0.2f

#define BM 64
#define BK 64

#define NB 196            // ceil(NN/256) coarse bins (dst>>8)
#define RECTOT (EE + NN)  // edges + self-loops
#define PCHUNK 4096       // records per partition block
#define SEGCAP 12288      // LDS staging capacity for one segment

// ---------------- CSR build: MSD counting sort by dst ----------------

__global__ void initcsr_kernel(int* __restrict__ hist1, int* __restrict__ fill1,
                               int* __restrict__ rowptr) {
    int t = threadIdx.x;
    if (t < NB) { hist1[t] = 0; fill1[t] = 0; }
    if (t == 0) rowptr[NN] = RECTOT;
}

__global__ __launch_bounds__(256) void hist_hi_kernel(const int* __restrict__ dst,
                                                      int* __restrict__ hist1) {
    __shared__ int lh[NB];
    int t = threadIdx.x;
    if (t < NB) lh[t] = 0;
    __syncthreads();
    int base = blockIdx.x * PCHUNK;
    #pragma unroll
    for (int j = 0; j < 16; ++j) {
        int i = base + j * 256 + t;
        if (i < RECTOT) {
            int d = (i < EE) ? dst[i] : (i - EE);
            atomicAdd(&lh[d >> 8], 1);
        }
    }
    __syncthreads();
    if (t < NB && lh[t]) atomicAdd(&hist1[t], lh[t]);
}

__global__ void scan_hi_kernel(const int* __restrict__ hist1, int* __restrict__ binStart) {
    int t = threadIdx.x, lane = t & 63, w = t >> 6;
    __shared__ int wsum[4];
    int v = (t < NB) ? hist1[t] : 0;
    int s = v;
    #pragma unroll
    for (int off = 1; off < 64; off <<= 1) {
        int u = __shfl_up(s, off);
        if (lane >= off) s += u;
    }
    if (lane == 63) wsum[w] = s;
    __syncthreads();
    int add = 0;
    for (int i = 0; i < w; ++i) add += wsum[i];
    int excl = add + s - v;
    if (t <= NB) binStart[t] = excl;
}

__global__ __launch_bounds__(256) void partition_kernel(
        const int* __restrict__ src, const int* __restrict__ dst,
        const int* __restrict__ binStart, int* __restrict__ fill1,
        uint2* __restrict__ bucket) {
    __shared__ int bh[NB], bbase[NB], sbase[NB];
    int t = threadIdx.x;
    if (t < NB) { bh[t] = 0; sbase[t] = binStart[t]; }
    __syncthreads();
    int base = blockIdx.x * PCHUNK;
    int dv[16], sv[16], lr[16];
    #pragma unroll
    for (int j = 0; j < 16; ++j) {
        int i = base + j * 256 + t;
        bool valid = i < RECTOT;
        int d = -1, s = 0;
        if (valid) {
            if (i < EE) { d = dst[i]; s = src[i]; }
            else        { d = i - EE; s = d; }
        }
        dv[j] = d; sv[j] = s;
        lr[j] = valid ? atomicAdd(&bh[d >> 8], 1) : 0;
    }
    __syncthreads();
    if (t < NB && bh[t]) bbase[t] = atomicAdd(&fill1[t], bh[t]);
    __syncthreads();
    #pragma unroll
    for (int j = 0; j < 16; ++j) {
        if (dv[j] >= 0) {
            int bin = dv[j] >> 8;
            bucket[sbase[bin] + bbase[bin] + lr[j]] =
                make_uint2((unsigned)dv[j], (unsigned)sv[j]);
        }
    }
}

// one block per coarse bin: LDS counting sort by dst&255, emit ushort col + rowptr
__global__ __launch_bounds__(256) void seg_sort_kernel(
        const uint2* __restrict__ bucket, const int* __restrict__ binStart,
        int* __restrict__ rowptr, unsigned short* __restrict__ col) {
    __shared__ uint2 stage[SEGCAP];
    __shared__ int h2[256], b2[256], c2[256];
    __shared__ int wsum[4];
    int t = threadIdx.x, lane = t & 63, w = t >> 6;
    int b = blockIdx.x;
    int segbase = binStart[b], segend = binStart[b + 1];
    int len = segend - segbase;
    h2[t] = 0; c2[t] = 0;
    __syncthreads();
    bool inLds = (len <= SEGCAP);
    if (inLds) {
        for (int i = t; i < len; i += 256) {
            uint2 r = bucket[segbase + i];
            stage[i] = r;
            atomicAdd(&h2[r.x & 255], 1);
        }
    } else {
        for (int i = t; i < len; i += 256) {
            uint2 r = bucket[segbase + i];
            atomicAdd(&h2[r.x & 255], 1);
        }
    }
    __syncthreads();
    int v = h2[t], s = v;
    #pragma unroll
    for (int off = 1; off < 64; off <<= 1) {
        int u = __shfl_up(s, off);
        if (lane >= off) s += u;
    }
    if (lane == 63) wsum[w] = s;
    __syncthreads();
    int add = 0;
    for (int i = 0; i < w; ++i) add += wsum[i];
    int excl = add + s - v;
    b2[t] = excl;
    int d = (b << 8) + t;
    if (d < NN) rowptr[d] = segbase + excl;
    __syncthreads();
    if (inLds) {
        for (int i = t; i < len; i += 256) {
            uint2 r = stage[i];
            int low = r.x & 255;
            int pos = b2[low] + atomicAdd(&c2[low], 1);
            col[segbase + pos] = (unsigned short)r.y;
        }
    } else {
        for (int i = t; i < len; i += 256) {
            uint2 r = bucket[segbase + i];
            int low = r.x & 255;
            int pos = b2[low] + atomicAdd(&c2[low], 1);
            col[segbase + pos] = (unsigned short)r.y;
        }
    }
}

// ---------------- tiled GEMM + fused attention-logit epilogue ----------------
// h row-major [node][64]; a_s/a_d [node][head].
__global__ __launch_bounds__(256) void gemm_att_kernel(
        const float* __restrict__ x, const float* __restrict__ W,
        const float* __restrict__ att_src, const float* __restrict__ att_dst,
        float* __restrict__ h, float* __restrict__ a_s, float* __restrict__ a_d,
        int n, int K) {
    __shared__ float Xs[BM][BK + 4];
    __shared__ float Ws[BK][OUTC + 4];
    int tid = (int)threadIdx.x;
    int tx = tid & 15, ty = tid >> 4;
    int row0 = blockIdx.x * BM;

    float acc[4][4] = {};

    for (int k0 = 0; k0 < K; k0 += BK) {
        {
            int r = tid >> 2;
            int kc = (tid & 3) * 16;
            int row = row0 + r; if (row >= n) row = n - 1;
            const float4* xp = (const float4*)(x + (size_t)row * K + k0 + kc);
            float4 v0 = xp[0], v1 = xp[1], v2 = xp[2], v3 = xp[3];
            *(float4*)&Xs[r][kc]      = v0;
            *(float4*)&Xs[r][kc + 4]  = v1;
            *(float4*)&Xs[r][kc + 8]  = v2;
            *(float4*)&Xs[r][kc + 12] = v3;
        }
        {
            int k = tid >> 2;
            int c = (tid & 3) * 16;
            const float4* wp = (const float4*)(W + (size_t)(k0 + k) * OUTC + c);
            float4 v0 = wp[0], v1 = wp[1], v2 = wp[2], v3 = wp[3];
            *(float4*)&Ws[k][c]      = v0;
            *(float4*)&Ws[k][c + 4]  = v1;
            *(float4*)&Ws[k][c + 8]  = v2;
            *(float4*)&Ws[k][c + 12] = v3;
        }
        __syncthreads();
        #pragma unroll 8
        for (int k = 0; k < BK; ++k) {
            float4 wv = *(const float4*)&Ws[k][tx * 4];
            float x0 = Xs[ty * 4 + 0][k];
            float x1 = Xs[ty * 4 + 1][k];
            float x2 = Xs[ty * 4 + 2][k];
            float x3 = Xs[ty * 4 + 3][k];
            acc[0][0] = fmaf(x0, wv.x, acc[0][0]); acc[0][1] = fmaf(x0, wv.y, acc[0][1]);
            acc[0][2] = fmaf(x0, wv.z, acc[0][2]); acc[0][3] = fmaf(x0, wv.w, acc[0][3]);
            acc[1][0] = fmaf(x1, wv.x, acc[1][0]); acc[1][1] = fmaf(x1, wv.y, acc[1][1]);
            acc[1][2] = fmaf(x1, wv.z, acc[1][2]); acc[1][3] = fmaf(x1, wv.w, acc[1][3]);
            acc[2][0] = fmaf(x2, wv.x, acc[2][0]); acc[2][1] = fmaf(x2, wv.y, acc[2][1]);
            acc[2][2] = fmaf(x2, wv.z, acc[2][2]); acc[2][3] = fmaf(x2, wv.w, acc[2][3]);
            acc[3][0] = fmaf(x3, wv.x, acc[3][0]); acc[3][1] = fmaf(x3, wv.y, acc[3][1]);
            acc[3][2] = fmaf(x3, wv.z, acc[3][2]); acc[3][3] = fmaf(x3, wv.w, acc[3][3]);
        }
        __syncthreads();
    }

    float as0 = att_src[tx * 4 + 0], as1 = att_src[tx * 4 + 1];
    float as2 = att_src[tx * 4 + 2], as3 = att_src[tx * 4 + 3];
    float ad0 = att_dst[tx * 4 + 0], ad1 = att_dst[tx * 4 + 1];
    float ad2 = att_dst[tx * 4 + 2], ad3 = att_dst[tx * 4 + 3];
    int head = tx >> 2;
    #pragma unroll
    for (int i = 0; i < 4; ++i) {
        int row = row0 + ty * 4 + i;
        bool ok = row < n;
        if (ok) {
            float4 hv = make_float4(acc[i][0], acc[i][1], acc[i][2], acc[i][3]);
            *(float4*)(h + (size_t)row * OUTC + tx * 4) = hv;
        }
        float ps = acc[i][0] * as0 + acc[i][1] * as1 + acc[i][2] * as2 + acc[i][3] * as3;
        float pd = acc[i][0] * ad0 + acc[i][1] * ad1 + acc[i][2] * ad2 + acc[i][3] * ad3;
        ps += __shfl_xor(ps, 1); ps += __shfl_xor(ps, 2);
        pd += __shfl_xor(pd, 1); pd += __shfl_xor(pd, 2);
        if (ok && (tx & 3) == 0) {
            a_s[row * HEADS + head] = ps;
            a_d[row * HEADS + head] = pd;
        }
    }
}

// ---------------- segment softmax + aggregation ----------------
// Wave = 1 node: 4 edge-slots x 16 channel-lanes (float4 -> one instr covers
// the full 256-B h row = 2 full cache lines). 2-deep unroll: 8 rows (16
// lines) in flight per wave for max miss-level parallelism.
__global__ __launch_bounds__(256) void gat_aggr_kernel(
        const int* __restrict__ rowptr, const unsigned short* __restrict__ col,
        const float* __restrict__ h, const float* __restrict__ a_s,
        const float* __restrict__ a_d, const float* __restrict__ bias,
        float* __restrict__ out, int n, int do_relu) {
    int node = __builtin_amdgcn_readfirstlane(
        (int)((blockIdx.x * 256u + threadIdx.x) >> 6));
    if (node >= n) return;
    int lane = (int)(threadIdx.x & 63);
    int slot = lane >> 4;   // edge slot 0..3
    int cl   = lane & 15;   // float4 index: channels 4cl..4cl+3
    int head = cl >> 2;

    int beg = rowptr[node], end = rowptr[node + 1];
    float ad_h = a_d[(node << 2) | head];
    const float4* __restrict__ hp = (const float4*)h;   // row = 16 float4

    float4 acc = make_float4(0.f, 0.f, 0.f, 0.f);
    float den = 0.f;
    int e = beg + slot;
    for (; e + 4 < end; e += 8) {
        int s0 = (int)col[e], s1 = (int)col[e + 4];
        float as0 = a_s[(s0 << 2) | head];
        float as1 = a_s[(s1 << 2) | head];
        float4 h0 = hp[(s0 << 4) | cl];
        float4 h1 = hp[(s1 << 4) | cl];
        float x0 = as0 + ad_h; x0 = fmaxf(x0, NEG_SLOPE * x0);
        float x1 = as1 + ad_h; x1 = fmaxf(x1, NEG_SLOPE * x1);
        float e0 = __expf(x0), e1 = __expf(x1);
        acc.x = fmaf(e0, h0.x, acc.x); acc.y = fmaf(e0, h0.y, acc.y);
        acc.z = fmaf(e0, h0.z, acc.z); acc.w = fmaf(e0, h0.w, acc.w);
        acc.x = fmaf(e1, h1.x, acc.x); acc.y = fmaf(e1, h1.y, acc.y);
        acc.z = fmaf(e1, h1.z, acc.z); acc.w = fmaf(e1, h1.w, acc.w);
        den += e0 + e1;
    }
    for (; e < end; e += 4) {
        int s0 = (int)col[e];
        float as0 = a_s[(s0 << 2) | head];
        float4 h0 = hp[(s0 << 4) | cl];
        float x0 = as0 + ad_h; x0 = fmaxf(x0, NEG_SLOPE * x0);
        float e0 = __expf(x0);
        acc.x = fmaf(e0, h0.x, acc.x); acc.y = fmaf(e0, h0.y, acc.y);
        acc.z = fmaf(e0, h0.z, acc.z); acc.w = fmaf(e0, h0.w, acc.w);
        den += e0;
    }
    // reduce across the 4 slots (lane bits 4,5)
    acc.x += __shfl_xor(acc.x, 16); acc.y += __shfl_xor(acc.y, 16);
    acc.z += __shfl_xor(acc.z, 16); acc.w += __shfl_xor(acc.w, 16);
    den   += __shfl_xor(den, 16);
    acc.x += __shfl_xor(acc.x, 32); acc.y += __shfl_xor(acc.y, 32);
    acc.z += __shfl_xor(acc.z, 32); acc.w += __shfl_xor(acc.w, 32);
    den   += __shfl_xor(den, 32);
    if (slot == 0) {
        float inv = 1.0f / (den + 1e-16f);
        float4 bv = ((const float4*)bias)[cl];
        float rx = fmaf(acc.x, inv, bv.x);
        float ry = fmaf(acc.y, inv, bv.y);
        float rz = fmaf(acc.z, inv, bv.z);
        float rw = fmaf(acc.w, inv, bv.w);
        if (do_relu) {
            rx = fmaxf(rx, 0.f); ry = fmaxf(ry, 0.f);
            rz = fmaxf(rz, 0.f); rw = fmaxf(rw, 0.f);
        }
        ((float4*)out)[(node << 4) | cl] = make_float4(rx, ry, rz, rw);
    }
}

extern "C" void kernel_launch(void* const* d_in, const int* in_sizes, int n_in,
                              void* d_out, int out_size, void* d_ws, size_t ws_size,
                              hipStream_t stream) {
    const float* x  = (const float*)d_in[0];
    const int*   ei = (const int*)d_in[1];
    const int*   srcv = ei;         // edge_index[0]
    const int*   dstv = ei + EE;    // edge_index[1]

    const float* W[3]  = { (const float*)d_in[2], (const float*)d_in[6],  (const float*)d_in[10] };
    const float* AS[3] = { (const float*)d_in[3], (const float*)d_in[7],  (const float*)d_in[11] };
    const float* AD[3] = { (const float*)d_in[4], (const float*)d_in[8],  (const float*)d_in[12] };
    const float* B[3]  = { (const float*)d_in[5], (const float*)d_in[9],  (const float*)d_in[13] };

    char* ws = (char*)d_ws;
    size_t off = 0;
    auto carve = [&](size_t bytes) -> char* {
        char* p = ws + off;
        off = (off + bytes + 255) & ~(size_t)255;
        return p;
    };
    int*            rowptr   = (int*)carve((NN + 1) * sizeof(int));
    int*            hist1    = (int*)carve(NB * sizeof(int));
    int*            fill1    = (int*)carve(NB * sizeof(int));
    int*            binStart = (int*)carve((NB + 1) * sizeof(int));
    unsigned short* colv     = (unsigned short*)carve((size_t)RECTOT * sizeof(unsigned short));
    // bucket (13.2 MB) dead after seg_sort; hbuf (12.8 MB) first written after. Alias.
    char*  regionA  = carve((size_t)RECTOT * sizeof(uint2));
    uint2* bucket   = (uint2*)regionA;
    float* hbuf     = (float*)regionA;               // row-major [NN][64]
    float* xbuf     = (float*)carve((size_t)NN * OUTC * sizeof(float));
    float* a_s      = (float*)carve((size_t)NN * HEADS * sizeof(float));  // [NN][4]
    float* a_d      = (float*)carve((size_t)NN * HEADS * sizeof(float));  // [NN][4]

    // ---- CSR build: MSD counting sort (graph identical across layers) ----
    int pgrid = (RECTOT + PCHUNK - 1) / PCHUNK;
    initcsr_kernel<<<1, 256, 0, stream>>>(hist1, fill1, rowptr);
    hist_hi_kernel<<<pgrid, 256, 0, stream>>>(dstv, hist1);
    scan_hi_kernel<<<1, 256, 0, stream>>>(hist1, binStart);
    partition_kernel<<<pgrid, 256, 0, stream>>>(srcv, dstv, binStart, fill1, bucket);
    seg_sort_kernel<<<NB, 256, 0, stream>>>(bucket, binStart, rowptr, colv);

    int grid_gemm = (NN + BM - 1) / BM;
    int grid_aggr = (NN + 3) / 4;

    // ---- layer 0 (K=128) ----
    gemm_att_kernel<<<grid_gemm, 256, 0, stream>>>(x, W[0], AS[0], AD[0], hbuf, a_s, a_d, NN, 128);
    gat_aggr_kernel<<<grid_aggr, 256, 0, stream>>>(rowptr, colv, hbuf, a_s, a_d, B[0], xbuf, NN, 1);
    // ---- layer 1 (K=64) ----
    gemm_att_kernel<<<grid_gemm, 256, 0, stream>>>(xbuf, W[1], AS[1], AD[1], hbuf, a_s, a_d, NN, 64);
    gat_aggr_kernel<<<grid_aggr, 256, 0, stream>>>(rowptr, colv, hbuf, a_s, a_d, B[1], xbuf, NN, 1);
    // ---- layer 2 (K=64, no relu) -> d_out ----
    gemm_att_kernel<<<grid_gemm, 256, 0, stream>>>(xbuf, W[2], AS[2], AD[2], hbuf, a_s, a_d, NN, 64);
    gat_aggr_kernel<<<grid_aggr, 256, 0, stream>>>(rowptr, colv, hbuf, a_s, a_d, B[2], (float*)d_out, NN, 0);
}

// Round 7
// 242.214 us; speedup vs baseline: 1.7470x; 1.1603x over previous
//
#include <hip/hip_runtime.h>
#include <hip/hip_fp16.h>
#include <math.h>

#define NN 50000
#define EE 1600000
#define HEADS 4
#define OUTC 64
#define NEG_SLOPE 0.2f

#define BM 64
#define BK 64

#define NB 196            // ceil(NN/256) coarse bins (dst>>8)
#define RECTOT (EE + NN)  // edges + self-loops
#define PCHUNK 4096       // records per partition block
#define SEGCAP 12288      // LDS staging capacity for one segment

// ---------------- CSR build: MSD counting sort by dst ----------------

__global__ void initcsr_kernel(int* __restrict__ hist1, int* __restrict__ fill1,
                               int* __restrict__ rowptr) {
    int t = threadIdx.x;
    if (t < NB) { hist1[t] = 0; fill1[t] = 0; }
    if (t == 0) rowptr[NN] = RECTOT;
}

__global__ __launch_bounds__(256) void hist_hi_kernel(const int* __restrict__ dst,
                                                      int* __restrict__ hist1) {
    __shared__ int lh[NB];
    int t = threadIdx.x;
    if (t < NB) lh[t] = 0;
    __syncthreads();
    int base = blockIdx.x * PCHUNK;
    #pragma unroll
    for (int j = 0; j < 16; ++j) {
        int i = base + j * 256 + t;
        if (i < RECTOT) {
            int d = (i < EE) ? dst[i] : (i - EE);
            atomicAdd(&lh[d >> 8], 1);
        }
    }
    __syncthreads();
    if (t < NB && lh[t]) atomicAdd(&hist1[t], lh[t]);
}

__global__ void scan_hi_kernel(const int* __restrict__ hist1, int* __restrict__ binStart) {
    int t = threadIdx.x, lane = t & 63, w = t >> 6;
    __shared__ int wsum[4];
    int v = (t < NB) ? hist1[t] : 0;
    int s = v;
    #pragma unroll
    for (int off = 1; off < 64; off <<= 1) {
        int u = __shfl_up(s, off);
        if (lane >= off) s += u;
    }
    if (lane == 63) wsum[w] = s;
    __syncthreads();
    int add = 0;
    for (int i = 0; i < w; ++i) add += wsum[i];
    int excl = add + s - v;
    if (t <= NB) binStart[t] = excl;
}

__global__ __launch_bounds__(256) void partition_kernel(
        const int* __restrict__ src, const int* __restrict__ dst,
        const int* __restrict__ binStart, int* __restrict__ fill1,
        uint2* __restrict__ bucket) {
    __shared__ int bh[NB], bbase[NB], sbase[NB];
    int t = threadIdx.x;
    if (t < NB) { bh[t] = 0; sbase[t] = binStart[t]; }
    __syncthreads();
    int base = blockIdx.x * PCHUNK;
    int dv[16], sv[16], lr[16];
    #pragma unroll
    for (int j = 0; j < 16; ++j) {
        int i = base + j * 256 + t;
        bool valid = i < RECTOT;
        int d = -1, s = 0;
        if (valid) {
            if (i < EE) { d = dst[i]; s = src[i]; }
            else        { d = i - EE; s = d; }
        }
        dv[j] = d; sv[j] = s;
        lr[j] = valid ? atomicAdd(&bh[d >> 8], 1) : 0;
    }
    __syncthreads();
    if (t < NB && bh[t]) bbase[t] = atomicAdd(&fill1[t], bh[t]);
    __syncthreads();
    #pragma unroll
    for (int j = 0; j < 16; ++j) {
        if (dv[j] >= 0) {
            int bin = dv[j] >> 8;
            bucket[sbase[bin] + bbase[bin] + lr[j]] =
                make_uint2((unsigned)dv[j], (unsigned)sv[j]);
        }
    }
}

// one block per coarse bin: LDS counting sort by dst&255, emit ushort col + rowptr
__global__ __launch_bounds__(256) void seg_sort_kernel(
        const uint2* __restrict__ bucket, const int* __restrict__ binStart,
        int* __restrict__ rowptr, unsigned short* __restrict__ col) {
    __shared__ uint2 stage[SEGCAP];
    __shared__ int h2[256], b2[256], c2[256];
    __shared__ int wsum[4];
    int t = threadIdx.x, lane = t & 63, w = t >> 6;
    int b = blockIdx.x;
    int segbase = binStart[b], segend = binStart[b + 1];
    int len = segend - segbase;
    h2[t] = 0; c2[t] = 0;
    __syncthreads();
    bool inLds = (len <= SEGCAP);
    if (inLds) {
        for (int i = t; i < len; i += 256) {
            uint2 r = bucket[segbase + i];
            stage[i] = r;
            atomicAdd(&h2[r.x & 255], 1);
        }
    } else {
        for (int i = t; i < len; i += 256) {
            uint2 r = bucket[segbase + i];
            atomicAdd(&h2[r.x & 255], 1);
        }
    }
    __syncthreads();
    int v = h2[t], s = v;
    #pragma unroll
    for (int off = 1; off < 64; off <<= 1) {
        int u = __shfl_up(s, off);
        if (lane >= off) s += u;
    }
    if (lane == 63) wsum[w] = s;
    __syncthreads();
    int add = 0;
    for (int i = 0; i < w; ++i) add += wsum[i];
    int excl = add + s - v;
    b2[t] = excl;
    int d = (b << 8) + t;
    if (d < NN) rowptr[d] = segbase + excl;
    __syncthreads();
    if (inLds) {
        for (int i = t; i < len; i += 256) {
            uint2 r = stage[i];
            int low = r.x & 255;
            int pos = b2[low] + atomicAdd(&c2[low], 1);
            col[segbase + pos] = (unsigned short)r.y;
        }
    } else {
        for (int i = t; i < len; i += 256) {
            uint2 r = bucket[segbase + i];
            int low = r.x & 255;
            int pos = b2[low] + atomicAdd(&c2[low], 1);
            col[segbase + pos] = (unsigned short)r.y;
        }
    }
}

// ---------------- tiled GEMM + fused attention-logit epilogue ----------------
// h written fp16 (layers 0,1: h16 != null) or fp32 (layer 2).
__global__ __launch_bounds__(256) void gemm_att_kernel(
        const float* __restrict__ x, const float* __restrict__ W,
        const float* __restrict__ att_src, const float* __restrict__ att_dst,
        float* __restrict__ h, __half* __restrict__ h16,
        float* __restrict__ a_s, float* __restrict__ a_d,
        int n, int K) {
    __shared__ float Xs[BM][BK + 4];
    __shared__ float Ws[BK][OUTC + 4];
    int tid = (int)threadIdx.x;
    int tx = tid & 15, ty = tid >> 4;
    int row0 = blockIdx.x * BM;

    float acc[4][4] = {};

    for (int k0 = 0; k0 < K; k0 += BK) {
        {
            int r = tid >> 2;
            int kc = (tid & 3) * 16;
            int row = row0 + r; if (row >= n) row = n - 1;
            const float4* xp = (const float4*)(x + (size_t)row * K + k0 + kc);
            float4 v0 = xp[0], v1 = xp[1], v2 = xp[2], v3 = xp[3];
            *(float4*)&Xs[r][kc]      = v0;
            *(float4*)&Xs[r][kc + 4]  = v1;
            *(float4*)&Xs[r][kc + 8]  = v2;
            *(float4*)&Xs[r][kc + 12] = v3;
        }
        {
            int k = tid >> 2;
            int c = (tid & 3) * 16;
            const float4* wp = (const float4*)(W + (size_t)(k0 + k) * OUTC + c);
            float4 v0 = wp[0], v1 = wp[1], v2 = wp[2], v3 = wp[3];
            *(float4*)&Ws[k][c]      = v0;
            *(float4*)&Ws[k][c + 4]  = v1;
            *(float4*)&Ws[k][c + 8]  = v2;
            *(float4*)&Ws[k][c + 12] = v3;
        }
        __syncthreads();
        #pragma unroll 8
        for (int k = 0; k < BK; ++k) {
            float4 wv = *(const float4*)&Ws[k][tx * 4];
            float x0 = Xs[ty * 4 + 0][k];
            float x1 = Xs[ty * 4 + 1][k];
            float x2 = Xs[ty * 4 + 2][k];
            float x3 = Xs[ty * 4 + 3][k];
            acc[0][0] = fmaf(x0, wv.x, acc[0][0]); acc[0][1] = fmaf(x0, wv.y, acc[0][1]);
            acc[0][2] = fmaf(x0, wv.z, acc[0][2]); acc[0][3] = fmaf(x0, wv.w, acc[0][3]);
            acc[1][0] = fmaf(x1, wv.x, acc[1][0]); acc[1][1] = fmaf(x1, wv.y, acc[1][1]);
            acc[1][2] = fmaf(x1, wv.z, acc[1][2]); acc[1][3] = fmaf(x1, wv.w, acc[1][3]);
            acc[2][0] = fmaf(x2, wv.x, acc[2][0]); acc[2][1] = fmaf(x2, wv.y, acc[2][1]);
            acc[2][2] = fmaf(x2, wv.z, acc[2][2]); acc[2][3] = fmaf(x2, wv.w, acc[2][3]);
            acc[3][0] = fmaf(x3, wv.x, acc[3][0]); acc[3][1] = fmaf(x3, wv.y, acc[3][1]);
            acc[3][2] = fmaf(x3, wv.z, acc[3][2]); acc[3][3] = fmaf(x3, wv.w, acc[3][3]);
        }
        __syncthreads();
    }

    float as0 = att_src[tx * 4 + 0], as1 = att_src[tx * 4 + 1];
    float as2 = att_src[tx * 4 + 2], as3 = att_src[tx * 4 + 3];
    float ad0 = att_dst[tx * 4 + 0], ad1 = att_dst[tx * 4 + 1];
    float ad2 = att_dst[tx * 4 + 2], ad3 = att_dst[tx * 4 + 3];
    int head = tx >> 2;
    #pragma unroll
    for (int i = 0; i < 4; ++i) {
        int row = row0 + ty * 4 + i;
        bool ok = row < n;
        if (ok) {
            if (h16) {
                union { __half2 h2[2]; uint2 u; } pk;
                pk.h2[0] = __floats2half2_rn(acc[i][0], acc[i][1]);
                pk.h2[1] = __floats2half2_rn(acc[i][2], acc[i][3]);
                *(uint2*)(h16 + (size_t)row * OUTC + tx * 4) = pk.u;
            } else {
                float4 hv = make_float4(acc[i][0], acc[i][1], acc[i][2], acc[i][3]);
                *(float4*)(h + (size_t)row * OUTC + tx * 4) = hv;
            }
        }
        float ps = acc[i][0] * as0 + acc[i][1] * as1 + acc[i][2] * as2 + acc[i][3] * as3;
        float pd = acc[i][0] * ad0 + acc[i][1] * ad1 + acc[i][2] * ad2 + acc[i][3] * ad3;
        ps += __shfl_xor(ps, 1); ps += __shfl_xor(ps, 2);
        pd += __shfl_xor(pd, 1); pd += __shfl_xor(pd, 2);
        if (ok && (tx & 3) == 0) {
            a_s[row * HEADS + head] = ps;
            a_d[row * HEADS + head] = pd;
        }
    }
}

// ---------------- aggregation, fp16 h (hidden layers) ----------------
// Row = 64 halves = 128 B = ONE cache line; 16 lanes x uint2 cover it.
__global__ __launch_bounds__(256) void gat_aggr16_kernel(
        const int* __restrict__ rowptr, const unsigned short* __restrict__ col,
        const __half* __restrict__ h16, const float* __restrict__ a_s,
        const float* __restrict__ a_d, const float* __restrict__ bias,
        float* __restrict__ out, int n) {
    int node = __builtin_amdgcn_readfirstlane(
        (int)((blockIdx.x * 256u + threadIdx.x) >> 6));
    if (node >= n) return;
    int lane = (int)(threadIdx.x & 63);
    int slot = lane >> 4;   // edge slot 0..3
    int cl   = lane & 15;   // uint2 index: channels 4cl..4cl+3
    int head = cl >> 2;

    int beg = rowptr[node], end = rowptr[node + 1];
    float ad_h = a_d[(node << 2) | head];
    const uint2* __restrict__ hp = (const uint2*)h16;   // row = 16 uint2

    float4 acc = make_float4(0.f, 0.f, 0.f, 0.f);
    float den = 0.f;
    int e = beg + slot;
    for (; e + 4 < end; e += 8) {
        int s0 = (int)col[e], s1 = (int)col[e + 4];
        float as0 = a_s[(s0 << 2) | head];
        float as1 = a_s[(s1 << 2) | head];
        uint2 r0 = hp[(s0 << 4) | cl];
        uint2 r1 = hp[(s1 << 4) | cl];
        union { uint2 u; __half2 h2[2]; } p0, p1;
        p0.u = r0; p1.u = r1;
        float2 f00 = __half22float2(p0.h2[0]), f01 = __half22float2(p0.h2[1]);
        float2 f10 = __half22float2(p1.h2[0]), f11 = __half22float2(p1.h2[1]);
        float x0 = as0 + ad_h; x0 = fmaxf(x0, NEG_SLOPE * x0);
        float x1 = as1 + ad_h; x1 = fmaxf(x1, NEG_SLOPE * x1);
        float e0 = __expf(x0), e1 = __expf(x1);
        acc.x = fmaf(e0, f00.x, acc.x); acc.y = fmaf(e0, f00.y, acc.y);
        acc.z = fmaf(e0, f01.x, acc.z); acc.w = fmaf(e0, f01.y, acc.w);
        acc.x = fmaf(e1, f10.x, acc.x); acc.y = fmaf(e1, f10.y, acc.y);
        acc.z = fmaf(e1, f11.x, acc.z); acc.w = fmaf(e1, f11.y, acc.w);
        den += e0 + e1;
    }
    for (; e < end; e += 4) {
        int s0 = (int)col[e];
        float as0 = a_s[(s0 << 2) | head];
        uint2 r0 = hp[(s0 << 4) | cl];
        union { uint2 u; __half2 h2[2]; } p0;
        p0.u = r0;
        float2 f00 = __half22float2(p0.h2[0]), f01 = __half22float2(p0.h2[1]);
        float x0 = as0 + ad_h; x0 = fmaxf(x0, NEG_SLOPE * x0);
        float e0 = __expf(x0);
        acc.x = fmaf(e0, f00.x, acc.x); acc.y = fmaf(e0, f00.y, acc.y);
        acc.z = fmaf(e0, f01.x, acc.z); acc.w = fmaf(e0, f01.y, acc.w);
        den += e0;
    }
    acc.x += __shfl_xor(acc.x, 16); acc.y += __shfl_xor(acc.y, 16);
    acc.z += __shfl_xor(acc.z, 16); acc.w += __shfl_xor(acc.w, 16);
    den   += __shfl_xor(den, 16);
    acc.x += __shfl_xor(acc.x, 32); acc.y += __shfl_xor(acc.y, 32);
    acc.z += __shfl_xor(acc.z, 32); acc.w += __shfl_xor(acc.w, 32);
    den   += __shfl_xor(den, 32);
    if (slot == 0) {
        float inv = 1.0f / (den + 1e-16f);
        float4 bv = ((const float4*)bias)[cl];
        float rx = fmaf(acc.x, inv, bv.x);
        float ry = fmaf(acc.y, inv, bv.y);
        float rz = fmaf(acc.z, inv, bv.z);
        float rw = fmaf(acc.w, inv, bv.w);
        rx = fmaxf(rx, 0.f); ry = fmaxf(ry, 0.f);   // hidden layers always relu
        rz = fmaxf(rz, 0.f); rw = fmaxf(rw, 0.f);
        ((float4*)out)[(node << 4) | cl] = make_float4(rx, ry, rz, rw);
    }
}

// ---------------- aggregation, fp32 h (final layer) ----------------
__global__ __launch_bounds__(256) void gat_aggr_kernel(
        const int* __restrict__ rowptr, const unsigned short* __restrict__ col,
        const float* __restrict__ h, const float* __restrict__ a_s,
        const float* __restrict__ a_d, const float* __restrict__ bias,
        float* __restrict__ out, int n) {
    int node = __builtin_amdgcn_readfirstlane(
        (int)((blockIdx.x * 256u + threadIdx.x) >> 6));
    if (node >= n) return;
    int lane = (int)(threadIdx.x & 63);
    int slot = lane >> 4;
    int cl   = lane & 15;
    int head = cl >> 2;

    int beg = rowptr[node], end = rowptr[node + 1];
    float ad_h = a_d[(node << 2) | head];
    const float4* __restrict__ hp = (const float4*)h;

    float4 acc = make_float4(0.f, 0.f, 0.f, 0.f);
    float den = 0.f;
    int e = beg + slot;
    for (; e + 4 < end; e += 8) {
        int s0 = (int)col[e], s1 = (int)col[e + 4];
        float as0 = a_s[(s0 << 2) | head];
        float as1 = a_s[(s1 << 2) | head];
        float4 h0 = hp[(s0 << 4) | cl];
        float4 h1 = hp[(s1 << 4) | cl];
        float x0 = as0 + ad_h; x0 = fmaxf(x0, NEG_SLOPE * x0);
        float x1 = as1 + ad_h; x1 = fmaxf(x1, NEG_SLOPE * x1);
        float e0 = __expf(x0), e1 = __expf(x1);
        acc.x = fmaf(e0, h0.x, acc.x); acc.y = fmaf(e0, h0.y, acc.y);
        acc.z = fmaf(e0, h0.z, acc.z); acc.w = fmaf(e0, h0.w, acc.w);
        acc.x = fmaf(e1, h1.x, acc.x); acc.y = fmaf(e1, h1.y, acc.y);
        acc.z = fmaf(e1, h1.z, acc.z); acc.w = fmaf(e1, h1.w, acc.w);
        den += e0 + e1;
    }
    for (; e < end; e += 4) {
        int s0 = (int)col[e];
        float as0 = a_s[(s0 << 2) | head];
        float4 h0 = hp[(s0 << 4) | cl];
        float x0 = as0 + ad_h; x0 = fmaxf(x0, NEG_SLOPE * x0);
        float e0 = __expf(x0);
        acc.x = fmaf(e0, h0.x, acc.x); acc.y = fmaf(e0, h0.y, acc.y);
        acc.z = fmaf(e0, h0.z, acc.z); acc.w = fmaf(e0, h0.w, acc.w);
        den += e0;
    }
    acc.x += __shfl_xor(acc.x, 16); acc.y += __shfl_xor(acc.y, 16);
    acc.z += __shfl_xor(acc.z, 16); acc.w += __shfl_xor(acc.w, 16);
    den   += __shfl_xor(den, 16);
    acc.x += __shfl_xor(acc.x, 32); acc.y += __shfl_xor(acc.y, 32);
    acc.z += __shfl_xor(acc.z, 32); acc.w += __shfl_xor(acc.w, 32);
    den   += __shfl_xor(den, 32);
    if (slot == 0) {
        float inv = 1.0f / (den + 1e-16f);
        float4 bv = ((const float4*)bias)[cl];
        float rx = fmaf(acc.x, inv, bv.x);
        float ry = fmaf(acc.y, inv, bv.y);
        float rz = fmaf(acc.z, inv, bv.z);
        float rw = fmaf(acc.w, inv, bv.w);
        ((float4*)out)[(node << 4) | cl] = make_float4(rx, ry, rz, rw);
    }
}

extern "C" void kernel_launch(void* const* d_in, const int* in_sizes, int n_in,
                              void* d_out, int out_size, void* d_ws, size_t ws_size,
                              hipStream_t stream) {
    const float* x  = (const float*)d_in[0];
    const int*   ei = (const int*)d_in[1];
    const int*   srcv = ei;         // edge_index[0]
    const int*   dstv = ei + EE;    // edge_index[1]

    const float* W[3]  = { (const float*)d_in[2], (const float*)d_in[6],  (const float*)d_in[10] };
    const float* AS[3] = { (const float*)d_in[3], (const float*)d_in[7],  (const float*)d_in[11] };
    const float* AD[3] = { (const float*)d_in[4], (const float*)d_in[8],  (const float*)d_in[12] };
    const float* B[3]  = { (const float*)d_in[5], (const float*)d_in[9],  (const float*)d_in[13] };

    char* ws = (char*)d_ws;
    size_t off = 0;
    auto carve = [&](size_t bytes) -> char* {
        char* p = ws + off;
        off = (off + bytes + 255) & ~(size_t)255;
        return p;
    };
    int*            rowptr   = (int*)carve((NN + 1) * sizeof(int));
    int*            hist1    = (int*)carve(NB * sizeof(int));
    int*            fill1    = (int*)carve(NB * sizeof(int));
    int*            binStart = (int*)carve((NB + 1) * sizeof(int));
    unsigned short* colv     = (unsigned short*)carve((size_t)RECTOT * sizeof(unsigned short));
    // regionA time-shares: bucket (13.2 MB, dead after seg_sort) ->
    // h16 (6.4 MB, layers 0,1) -> hbuf fp32 (12.8 MB, layer 2).
    char*   regionA = carve((size_t)RECTOT * sizeof(uint2));
    uint2*  bucket  = (uint2*)regionA;
    float*  hbuf    = (float*)regionA;
    __half* h16     = (__half*)regionA;
    float* xbuf     = (float*)carve((size_t)NN * OUTC * sizeof(float));
    float* a_s      = (float*)carve((size_t)NN * HEADS * sizeof(float));
    float* a_d      = (float*)carve((size_t)NN * HEADS * sizeof(float));

    // ---- CSR build: MSD counting sort (graph identical across layers) ----
    int pgrid = (RECTOT + PCHUNK - 1) / PCHUNK;
    initcsr_kernel<<<1, 256, 0, stream>>>(hist1, fill1, rowptr);
    hist_hi_kernel<<<pgrid, 256, 0, stream>>>(dstv, hist1);
    scan_hi_kernel<<<1, 256, 0, stream>>>(hist1, binStart);
    partition_kernel<<<pgrid, 256, 0, stream>>>(srcv, dstv, binStart, fill1, bucket);
    seg_sort_kernel<<<NB, 256, 0, stream>>>(bucket, binStart, rowptr, colv);

    int grid_gemm = (NN + BM - 1) / BM;
    int grid_aggr = (NN + 3) / 4;

    // ---- layer 0 (K=128): fp16 h ----
    gemm_att_kernel<<<grid_gemm, 256, 0, stream>>>(x, W[0], AS[0], AD[0],
                                                   nullptr, h16, a_s, a_d, NN, 128);
    gat_aggr16_kernel<<<grid_aggr, 256, 0, stream>>>(rowptr, colv, h16, a_s, a_d, B[0], xbuf, NN);
    // ---- layer 1 (K=64): fp16 h ----
    gemm_att_kernel<<<grid_gemm, 256, 0, stream>>>(xbuf, W[1], AS[1], AD[1],
                                                   nullptr, h16, a_s, a_d, NN, 64);
    gat_aggr16_kernel<<<grid_aggr, 256, 0, stream>>>(rowptr, colv, h16, a_s, a_d, B[1], xbuf, NN);
    // ---- layer 2 (K=64): fp32 h, no relu -> d_out ----
    gemm_att_kernel<<<grid_gemm, 256, 0, stream>>>(xbuf, W[2], AS[2], AD[2],
                                                   hbuf, nullptr, a_s, a_d, NN, 64);
    gat_aggr_kernel<<<grid_aggr, 256, 0, stream>>>(rowptr, colv, hbuf, a_s, a_d, B[2], (float*)d_out, NN);
}

// Round 8
// 224.558 us; speedup vs baseline: 1.8843x; 1.0786x over previous
//
#include <hip/hip_runtime.h>
#include <hip/hip_fp16.h>
#include <math.h>

#define NN 50000
#define EE 1600000
#define HEADS 4
#define OUTC 64
#define NEG_SLOPE 0.2f

#define BM 64
#define BK 64

#define NB 196            // ceil(NN/256) coarse bins (dst>>8)
#define RECTOT (EE + NN)  // edges + self-loops
#define PCHUNK 4096       // records per partition block
#define SEGCAP 12288      // LDS staging capacity for one segment (uint, 48 KB)

// ---------------- CSR build: MSD counting sort by dst ----------------
// bucket record: ((dst & 255) << 16) | src   (src < 65536, 4 B/record)

__global__ void initcsr_kernel(int* __restrict__ hist1, int* __restrict__ fill1,
                               int* __restrict__ rowptr) {
    int t = threadIdx.x;
    if (t < NB) { hist1[t] = 0; fill1[t] = 0; }
    if (t == 0) rowptr[NN] = RECTOT;
}

__global__ __launch_bounds__(256) void hist_hi_kernel(const int* __restrict__ dst,
                                                      int* __restrict__ hist1) {
    __shared__ int lh[NB];
    int t = threadIdx.x;
    if (t < NB) lh[t] = 0;
    __syncthreads();
    int base = blockIdx.x * PCHUNK;
    #pragma unroll
    for (int j = 0; j < 16; ++j) {
        int i = base + j * 256 + t;
        if (i < RECTOT) {
            int d = (i < EE) ? dst[i] : (i - EE);
            atomicAdd(&lh[d >> 8], 1);
        }
    }
    __syncthreads();
    if (t < NB && lh[t]) atomicAdd(&hist1[t], lh[t]);
}

__global__ void scan_hi_kernel(const int* __restrict__ hist1, int* __restrict__ binStart) {
    int t = threadIdx.x, lane = t & 63, w = t >> 6;
    __shared__ int wsum[4];
    int v = (t < NB) ? hist1[t] : 0;
    int s = v;
    #pragma unroll
    for (int off = 1; off < 64; off <<= 1) {
        int u = __shfl_up(s, off);
        if (lane >= off) s += u;
    }
    if (lane == 63) wsum[w] = s;
    __syncthreads();
    int add = 0;
    for (int i = 0; i < w; ++i) add += wsum[i];
    int excl = add + s - v;
    if (t <= NB) binStart[t] = excl;
}

__global__ __launch_bounds__(256) void partition_kernel(
        const int* __restrict__ src, const int* __restrict__ dst,
        const int* __restrict__ binStart, int* __restrict__ fill1,
        unsigned* __restrict__ bucket) {
    __shared__ int bh[NB], bbase[NB], sbase[NB];
    int t = threadIdx.x;
    if (t < NB) { bh[t] = 0; sbase[t] = binStart[t]; }
    __syncthreads();
    int base = blockIdx.x * PCHUNK;
    int dv[16], sv[16], lr[16];
    #pragma unroll
    for (int j = 0; j < 16; ++j) {
        int i = base + j * 256 + t;
        bool valid = i < RECTOT;
        int d = -1, s = 0;
        if (valid) {
            if (i < EE) { d = dst[i]; s = src[i]; }
            else        { d = i - EE; s = d; }
        }
        dv[j] = d; sv[j] = s;
        lr[j] = valid ? atomicAdd(&bh[d >> 8], 1) : 0;
    }
    __syncthreads();
    if (t < NB && bh[t]) bbase[t] = atomicAdd(&fill1[t], bh[t]);
    __syncthreads();
    #pragma unroll
    for (int j = 0; j < 16; ++j) {
        if (dv[j] >= 0) {
            int bin = dv[j] >> 8;
            bucket[sbase[bin] + bbase[bin] + lr[j]] =
                ((unsigned)(dv[j] & 255) << 16) | (unsigned)sv[j];
        }
    }
}

// one block per coarse bin: LDS counting sort by dst&255, emit ushort col + rowptr
__global__ __launch_bounds__(256) void seg_sort_kernel(
        const unsigned* __restrict__ bucket, const int* __restrict__ binStart,
        int* __restrict__ rowptr, unsigned short* __restrict__ col) {
    __shared__ unsigned stage[SEGCAP];
    __shared__ int h2[256], b2[256], c2[256];
    __shared__ int wsum[4];
    int t = threadIdx.x, lane = t & 63, w = t >> 6;
    int b = blockIdx.x;
    int segbase = binStart[b], segend = binStart[b + 1];
    int len = segend - segbase;
    h2[t] = 0; c2[t] = 0;
    __syncthreads();
    bool inLds = (len <= SEGCAP);
    if (inLds) {
        for (int i = t; i < len; i += 256) {
            unsigned r = bucket[segbase + i];
            stage[i] = r;
            atomicAdd(&h2[(r >> 16) & 255], 1);
        }
    } else {
        for (int i = t; i < len; i += 256) {
            unsigned r = bucket[segbase + i];
            atomicAdd(&h2[(r >> 16) & 255], 1);
        }
    }
    __syncthreads();
    int v = h2[t], s = v;
    #pragma unroll
    for (int off = 1; off < 64; off <<= 1) {
        int u = __shfl_up(s, off);
        if (lane >= off) s += u;
    }
    if (lane == 63) wsum[w] = s;
    __syncthreads();
    int add = 0;
    for (int i = 0; i < w; ++i) add += wsum[i];
    int excl = add + s - v;
    b2[t] = excl;
    int d = (b << 8) + t;
    if (d < NN) rowptr[d] = segbase + excl;
    __syncthreads();
    if (inLds) {
        for (int i = t; i < len; i += 256) {
            unsigned r = stage[i];
            int low = (r >> 16) & 255;
            int pos = b2[low] + atomicAdd(&c2[low], 1);
            col[segbase + pos] = (unsigned short)(r & 0xFFFFu);
        }
    } else {
        for (int i = t; i < len; i += 256) {
            unsigned r = bucket[segbase + i];
            int low = (r >> 16) & 255;
            int pos = b2[low] + atomicAdd(&c2[low], 1);
            col[segbase + pos] = (unsigned short)(r & 0xFFFFu);
        }
    }
}

// ---------------- tiled GEMM + fused attention-logit epilogue ----------------
// Xt stored transposed [k][row] so the inner loop is 2x ds_read_b128 per k.
// h written fp16 (all layers); a_s/a_d fp32 exact.
__global__ __launch_bounds__(256) void gemm_att_kernel(
        const float* __restrict__ x, const float* __restrict__ W,
        const float* __restrict__ att_src, const float* __restrict__ att_dst,
        __half* __restrict__ h16,
        float* __restrict__ a_s, float* __restrict__ a_d,
        int n, int K) {
    __shared__ float Xt[BK][BM + 4];   // [k][row], stride 68
    __shared__ float Ws[BK][OUTC + 4];
    int tid = (int)threadIdx.x;
    int tx = tid & 15, ty = tid >> 4;
    int row0 = blockIdx.x * BM;

    float acc[4][4] = {};

    for (int k0 = 0; k0 < K; k0 += BK) {
        // stage X tile transposed: thread owns rows 4rb..4rb+3, k's 4kb..4kb+3
        {
            int rb = tid >> 4;          // 0..15
            int kb = tid & 15;          // 0..15
            float4 v0, v1, v2, v3;
            {
                int r0 = row0 + 4 * rb;
                int ra = r0 + 0; if (ra >= n) ra = n - 1;
                int rbx = r0 + 1; if (rbx >= n) rbx = n - 1;
                int rc = r0 + 2; if (rc >= n) rc = n - 1;
                int rd = r0 + 3; if (rd >= n) rd = n - 1;
                const float* xb = x + (size_t)k0 + 4 * kb;
                v0 = *(const float4*)(xb + (size_t)ra * K);
                v1 = *(const float4*)(xb + (size_t)rbx * K);
                v2 = *(const float4*)(xb + (size_t)rc * K);
                v3 = *(const float4*)(xb + (size_t)rd * K);
            }
            *(float4*)&Xt[4 * kb + 0][4 * rb] = make_float4(v0.x, v1.x, v2.x, v3.x);
            *(float4*)&Xt[4 * kb + 1][4 * rb] = make_float4(v0.y, v1.y, v2.y, v3.y);
            *(float4*)&Xt[4 * kb + 2][4 * rb] = make_float4(v0.z, v1.z, v2.z, v3.z);
            *(float4*)&Xt[4 * kb + 3][4 * rb] = make_float4(v0.w, v1.w, v2.w, v3.w);
        }
        // stage W tile
        {
            int k = tid >> 2;
            int c = (tid & 3) * 16;
            const float4* wp = (const float4*)(W + (size_t)(k0 + k) * OUTC + c);
            float4 v0 = wp[0], v1 = wp[1], v2 = wp[2], v3 = wp[3];
            *(float4*)&Ws[k][c]      = v0;
            *(float4*)&Ws[k][c + 4]  = v1;
            *(float4*)&Ws[k][c + 8]  = v2;
            *(float4*)&Ws[k][c + 12] = v3;
        }
        __syncthreads();
        #pragma unroll 8
        for (int k = 0; k < BK; ++k) {
            float4 xv = *(const float4*)&Xt[k][ty * 4];
            float4 wv = *(const float4*)&Ws[k][tx * 4];
            acc[0][0] = fmaf(xv.x, wv.x, acc[0][0]); acc[0][1] = fmaf(xv.x, wv.y, acc[0][1]);
            acc[0][2] = fmaf(xv.x, wv.z, acc[0][2]); acc[0][3] = fmaf(xv.x, wv.w, acc[0][3]);
            acc[1][0] = fmaf(xv.y, wv.x, acc[1][0]); acc[1][1] = fmaf(xv.y, wv.y, acc[1][1]);
            acc[1][2] = fmaf(xv.y, wv.z, acc[1][2]); acc[1][3] = fmaf(xv.y, wv.w, acc[1][3]);
            acc[2][0] = fmaf(xv.z, wv.x, acc[2][0]); acc[2][1] = fmaf(xv.z, wv.y, acc[2][1]);
            acc[2][2] = fmaf(xv.z, wv.z, acc[2][2]); acc[2][3] = fmaf(xv.z, wv.w, acc[2][3]);
            acc[3][0] = fmaf(xv.w, wv.x, acc[3][0]); acc[3][1] = fmaf(xv.w, wv.y, acc[3][1]);
            acc[3][2] = fmaf(xv.w, wv.z, acc[3][2]); acc[3][3] = fmaf(xv.w, wv.w, acc[3][3]);
        }
        __syncthreads();
    }

    float as0 = att_src[tx * 4 + 0], as1 = att_src[tx * 4 + 1];
    float as2 = att_src[tx * 4 + 2], as3 = att_src[tx * 4 + 3];
    float ad0 = att_dst[tx * 4 + 0], ad1 = att_dst[tx * 4 + 1];
    float ad2 = att_dst[tx * 4 + 2], ad3 = att_dst[tx * 4 + 3];
    int head = tx >> 2;
    #pragma unroll
    for (int i = 0; i < 4; ++i) {
        int row = row0 + ty * 4 + i;
        bool ok = row < n;
        if (ok) {
            union { __half2 h2[2]; uint2 u; } pk;
            pk.h2[0] = __floats2half2_rn(acc[i][0], acc[i][1]);
            pk.h2[1] = __floats2half2_rn(acc[i][2], acc[i][3]);
            *(uint2*)(h16 + (size_t)row * OUTC + tx * 4) = pk.u;
        }
        float ps = acc[i][0] * as0 + acc[i][1] * as1 + acc[i][2] * as2 + acc[i][3] * as3;
        float pd = acc[i][0] * ad0 + acc[i][1] * ad1 + acc[i][2] * ad2 + acc[i][3] * ad3;
        ps += __shfl_xor(ps, 1); ps += __shfl_xor(ps, 2);
        pd += __shfl_xor(pd, 1); pd += __shfl_xor(pd, 2);
        if (ok && (tx & 3) == 0) {
            a_s[row * HEADS + head] = ps;
            a_d[row * HEADS + head] = pd;
        }
    }
}

// ---------------- aggregation, fp16 h (all layers) ----------------
// Row = 64 halves = 128 B = ONE cache line; 16 lanes x uint2 cover it.
__global__ __launch_bounds__(256) void gat_aggr16_kernel(
        const int* __restrict__ rowptr, const unsigned short* __restrict__ col,
        const __half* __restrict__ h16, const float* __restrict__ a_s,
        const float* __restrict__ a_d, const float* __restrict__ bias,
        float* __restrict__ out, int n, int do_relu) {
    int node = __builtin_amdgcn_readfirstlane(
        (int)((blockIdx.x * 256u + threadIdx.x) >> 6));
    if (node >= n) return;
    int lane = (int)(threadIdx.x & 63);
    int slot = lane >> 4;   // edge slot 0..3
    int cl   = lane & 15;   // uint2 index: channels 4cl..4cl+3
    int head = cl >> 2;

    int beg = rowptr[node], end = rowptr[node + 1];
    float ad_h = a_d[(node << 2) | head];
    const uint2* __restrict__ hp = (const uint2*)h16;   // row = 16 uint2

    float4 acc = make_float4(0.f, 0.f, 0.f, 0.f);
    float den = 0.f;
    int e = beg + slot;
    for (; e + 4 < end; e += 8) {
        int s0 = (int)col[e], s1 = (int)col[e + 4];
        float as0 = a_s[(s0 << 2) | head];
        float as1 = a_s[(s1 << 2) | head];
        uint2 r0 = hp[(s0 << 4) | cl];
        uint2 r1 = hp[(s1 << 4) | cl];
        union { uint2 u; __half2 h2[2]; } p0, p1;
        p0.u = r0; p1.u = r1;
        float2 f00 = __half22float2(p0.h2[0]), f01 = __half22float2(p0.h2[1]);
        float2 f10 = __half22float2(p1.h2[0]), f11 = __half22float2(p1.h2[1]);
        float x0 = as0 + ad_h; x0 = fmaxf(x0, NEG_SLOPE * x0);
        float x1 = as1 + ad_h; x1 = fmaxf(x1, NEG_SLOPE * x1);
        float e0 = __expf(x0), e1 = __expf(x1);
        acc.x = fmaf(e0, f00.x, acc.x); acc.y = fmaf(e0, f00.y, acc.y);
        acc.z = fmaf(e0, f01.x, acc.z); acc.w = fmaf(e0, f01.y, acc.w);
        acc.x = fmaf(e1, f10.x, acc.x); acc.y = fmaf(e1, f10.y, acc.y);
        acc.z = fmaf(e1, f11.x, acc.z); acc.w = fmaf(e1, f11.y, acc.w);
        den += e0 + e1;
    }
    for (; e < end; e += 4) {
        int s0 = (int)col[e];
        float as0 = a_s[(s0 << 2) | head];
        uint2 r0 = hp[(s0 << 4) | cl];
        union { uint2 u; __half2 h2[2]; } p0;
        p0.u = r0;
        float2 f00 = __half22float2(p0.h2[0]), f01 = __half22float2(p0.h2[1]);
        float x0 = as0 + ad_h; x0 = fmaxf(x0, NEG_SLOPE * x0);
        float e0 = __expf(x0);
        acc.x = fmaf(e0, f00.x, acc.x); acc.y = fmaf(e0, f00.y, acc.y);
        acc.z = fmaf(e0, f01.x, acc.z); acc.w = fmaf(e0, f01.y, acc.w);
        den += e0;
    }
    acc.x += __shfl_xor(acc.x, 16); acc.y += __shfl_xor(acc.y, 16);
    acc.z += __shfl_xor(acc.z, 16); acc.w += __shfl_xor(acc.w, 16);
    den   += __shfl_xor(den, 16);
    acc.x += __shfl_xor(acc.x, 32); acc.y += __shfl_xor(acc.y, 32);
    acc.z += __shfl_xor(acc.z, 32); acc.w += __shfl_xor(acc.w, 32);
    den   += __shfl_xor(den, 32);
    if (slot == 0) {
        float inv = 1.0f / (den + 1e-16f);
        float4 bv = ((const float4*)bias)[cl];
        float rx = fmaf(acc.x, inv, bv.x);
        float ry = fmaf(acc.y, inv, bv.y);
        float rz = fmaf(acc.z, inv, bv.z);
        float rw = fmaf(acc.w, inv, bv.w);
        if (do_relu) {
            rx = fmaxf(rx, 0.f); ry = fmaxf(ry, 0.f);
            rz = fmaxf(rz, 0.f); rw = fmaxf(rw, 0.f);
        }
        ((float4*)out)[(node << 4) | cl] = make_float4(rx, ry, rz, rw);
    }
}

extern "C" void kernel_launch(void* const* d_in, const int* in_sizes, int n_in,
                              void* d_out, int out_size, void* d_ws, size_t ws_size,
                              hipStream_t stream) {
    const float* x  = (const float*)d_in[0];
    const int*   ei = (const int*)d_in[1];
    const int*   srcv = ei;         // edge_index[0]
    const int*   dstv = ei + EE;    // edge_index[1]

    const float* W[3]  = { (const float*)d_in[2], (const float*)d_in[6],  (const float*)d_in[10] };
    const float* AS[3] = { (const float*)d_in[3], (const float*)d_in[7],  (const float*)d_in[11] };
    const float* AD[3] = { (const float*)d_in[4], (const float*)d_in[8],  (const float*)d_in[12] };
    const float* B[3]  = { (const float*)d_in[5], (const float*)d_in[9],  (const float*)d_in[13] };

    char* ws = (char*)d_ws;
    size_t off = 0;
    auto carve = [&](size_t bytes) -> char* {
        char* p = ws + off;
        off = (off + bytes + 255) & ~(size_t)255;
        return p;
    };
    int*            rowptr   = (int*)carve((NN + 1) * sizeof(int));
    int*            hist1    = (int*)carve(NB * sizeof(int));
    int*            fill1    = (int*)carve(NB * sizeof(int));
    int*            binStart = (int*)carve((NB + 1) * sizeof(int));
    unsigned short* colv     = (unsigned short*)carve((size_t)RECTOT * sizeof(unsigned short));
    // regionA time-shares: bucket (6.6 MB uint, dead after seg_sort) ->
    // h16 (6.4 MB, all three layers).
    char*     regionA = carve((size_t)RECTOT * sizeof(unsigned));
    unsigned* bucket  = (unsigned*)regionA;
    __half*   h16     = (__half*)regionA;
    float* xbuf     = (float*)carve((size_t)NN * OUTC * sizeof(float));
    float* a_s      = (float*)carve((size_t)NN * HEADS * sizeof(float));
    float* a_d      = (float*)carve((size_t)NN * HEADS * sizeof(float));

    // ---- CSR build: MSD counting sort (graph identical across layers) ----
    int pgrid = (RECTOT + PCHUNK - 1) / PCHUNK;
    initcsr_kernel<<<1, 256, 0, stream>>>(hist1, fill1, rowptr);
    hist_hi_kernel<<<pgrid, 256, 0, stream>>>(dstv, hist1);
    scan_hi_kernel<<<1, 256, 0, stream>>>(hist1, binStart);
    partition_kernel<<<pgrid, 256, 0, stream>>>(srcv, dstv, binStart, fill1, bucket);
    seg_sort_kernel<<<NB, 256, 0, stream>>>(bucket, binStart, rowptr, colv);

    int grid_gemm = (NN + BM - 1) / BM;
    int grid_aggr = (NN + 3) / 4;

    // ---- layer 0 (K=128) ----
    gemm_att_kernel<<<grid_gemm, 256, 0, stream>>>(x, W[0], AS[0], AD[0],
                                                   h16, a_s, a_d, NN, 128);
    gat_aggr16_kernel<<<grid_aggr, 256, 0, stream>>>(rowptr, colv, h16, a_s, a_d, B[0], xbuf, NN, 1);
    // ---- layer 1 (K=64) ----
    gemm_att_kernel<<<grid_gemm, 256, 0, stream>>>(xbuf, W[1], AS[1], AD[1],
                                                   h16, a_s, a_d, NN, 64);
    gat_aggr16_kernel<<<grid_aggr, 256, 0, stream>>>(rowptr, colv, h16, a_s, a_d, B[1], xbuf, NN, 1);
    // ---- layer 2 (K=64, no relu) -> d_out ----
    gemm_att_kernel<<<grid_gemm, 256, 0, stream>>>(xbuf, W[2], AS[2], AD[2],
                                                   h16, a_s, a_d, NN, 64);
    gat_aggr16_kernel<<<grid_aggr, 256, 0, stream>>>(rowptr, colv, h16, a_s, a_d, B[2], (float*)d_out, NN, 0);
}